// Round 1
// baseline (321.431 us; speedup 1.0000x reference)
//
#include <hip/hip_runtime.h>
#include <hip/hip_bf16.h>

// VectorQuantizer: B=64, C=64, H=32, W=32, K=1024
// d_in[0]: inputs  [B,C,H,W] fp32  (4,194,304)
// d_in[1]: weight  [K,C]     fp32  (65,536)
// d_out (float32, concat):
//   [0,          4194304)  quantized_st [B,C,H,W]
//   [4194304,    4259840)  indices      [B,H,W]  (written as float)
//   [4259840,    4259904)  loss         [B]

#define VQ_C   64
#define VQ_K   1024
#define VQ_HW  1024          // H*W
#define VQ_B   64
#define VQ_ROWS (VQ_B * VQ_HW)   // 65536
#define BLOCK  256
#define NBLOCKS (VQ_ROWS / BLOCK) // 256

__global__ __launch_bounds__(BLOCK) void vq_main_kernel(
    const float* __restrict__ inp,     // [B,C,H,W]
    const float* __restrict__ w,       // [K,C]
    float* __restrict__ out_q,         // [B,C,H,W]
    float* __restrict__ out_idx,       // [B*H*W] as float
    float* __restrict__ partials)      // [NBLOCKS]
{
    __shared__ float se2[VQ_K];
    __shared__ float red[BLOCK];

    const int tid = threadIdx.x;

    // ---- precompute ||e_k||^2 into LDS (per block; weight is L2-hot) ----
    for (int k = tid; k < VQ_K; k += BLOCK) {
        const float* wr = w + k * VQ_C;
        float s0 = 0.f, s1 = 0.f, s2 = 0.f, s3 = 0.f;
        #pragma unroll
        for (int c = 0; c < VQ_C; c += 4) {
            s0 = fmaf(wr[c + 0], wr[c + 0], s0);
            s1 = fmaf(wr[c + 1], wr[c + 1], s1);
            s2 = fmaf(wr[c + 2], wr[c + 2], s2);
            s3 = fmaf(wr[c + 3], wr[c + 3], s3);
        }
        se2[k] = (s0 + s1) + (s2 + s3);
    }
    __syncthreads();

    // ---- load this thread's row x (strided by H*W per channel; coalesced across wave) ----
    const int r  = blockIdx.x * BLOCK + tid;   // row id in [0, 65536)
    const int b  = r >> 10;                    // / (H*W)
    const int hw = r & (VQ_HW - 1);

    const float* xin = inp + (size_t)b * (VQ_C * VQ_HW) + hw;
    float x[VQ_C];
    #pragma unroll
    for (int c = 0; c < VQ_C; ++c) x[c] = xin[(size_t)c * VQ_HW];

    float sx0 = 0.f, sx1 = 0.f, sx2 = 0.f, sx3 = 0.f;
    #pragma unroll
    for (int c = 0; c < VQ_C; c += 4) {
        sx0 = fmaf(x[c + 0], x[c + 0], sx0);
        sx1 = fmaf(x[c + 1], x[c + 1], sx1);
        sx2 = fmaf(x[c + 2], x[c + 2], sx2);
        sx3 = fmaf(x[c + 3], x[c + 3], sx3);
    }
    const float sx = (sx0 + sx1) + (sx2 + sx3);

    // ---- argmin over K codes; weight address is wave-uniform -> s_load path ----
    float best = 3.402823466e38f;
    int bestk = 0;
    for (int k = 0; k < VQ_K; ++k) {
        const float* wr = w + k * VQ_C;
        float d0 = 0.f, d1 = 0.f, d2 = 0.f, d3 = 0.f;
        #pragma unroll
        for (int c = 0; c < VQ_C; c += 4) {
            d0 = fmaf(wr[c + 0], x[c + 0], d0);
            d1 = fmaf(wr[c + 1], x[c + 1], d1);
            d2 = fmaf(wr[c + 2], x[c + 2], d2);
            d3 = fmaf(wr[c + 3], x[c + 3], d3);
        }
        const float dot = (d0 + d1) + (d2 + d3);
        const float d = (sx + se2[k]) - 2.f * dot;
        if (d < best) { best = d; bestk = k; }
    }

    // ---- epilogue: gather code, write quantized_st, accumulate loss ----
    const float* q = w + bestk * VQ_C;   // per-lane gather; weight is L1/L2-hot
    float* outr = out_q + (size_t)b * (VQ_C * VQ_HW) + hw;
    float sd0 = 0.f, sd1 = 0.f, sd2 = 0.f, sd3 = 0.f;
    #pragma unroll
    for (int c = 0; c < VQ_C; c += 4) {
        float q0 = q[c + 0], q1 = q[c + 1], q2 = q[c + 2], q3 = q[c + 3];
        float x0 = x[c + 0], x1 = x[c + 1], x2 = x[c + 2], x3 = x[c + 3];
        outr[(size_t)(c + 0) * VQ_HW] = x0 + (q0 - x0);
        outr[(size_t)(c + 1) * VQ_HW] = x1 + (q1 - x1);
        outr[(size_t)(c + 2) * VQ_HW] = x2 + (q2 - x2);
        outr[(size_t)(c + 3) * VQ_HW] = x3 + (q3 - x3);
        float e0 = q0 - x0, e1 = q1 - x1, e2 = q2 - x2, e3 = q3 - x3;
        sd0 = fmaf(e0, e0, sd0);
        sd1 = fmaf(e1, e1, sd1);
        sd2 = fmaf(e2, e2, sd2);
        sd3 = fmaf(e3, e3, sd3);
    }
    out_idx[r] = (float)bestk;

    // ---- block reduction of squared-diff for loss ----
    red[tid] = (sd0 + sd1) + (sd2 + sd3);
    __syncthreads();
    #pragma unroll
    for (int s = BLOCK / 2; s > 0; s >>= 1) {
        if (tid < s) red[tid] += red[tid + s];
        __syncthreads();
    }
    if (tid == 0) partials[blockIdx.x] = red[0];
}

__global__ __launch_bounds__(64) void vq_loss_kernel(
    const float* __restrict__ partials,  // [NBLOCKS], 4 blocks per b
    float* __restrict__ loss)            // [B]
{
    const int b = threadIdx.x;  // 64 threads, 1 block
    const float s = (partials[4 * b + 0] + partials[4 * b + 1])
                  + (partials[4 * b + 2] + partials[4 * b + 3]);
    const float L = s * (1.0f / 65536.0f);   // mean over C*H*W (power of 2, exact)
    loss[b] = L + 0.25f * L;                 // q_latent + COMMITMENT_COST * e_latent
}

extern "C" void kernel_launch(void* const* d_in, const int* in_sizes, int n_in,
                              void* d_out, int out_size, void* d_ws, size_t ws_size,
                              hipStream_t stream) {
    const float* inp = (const float*)d_in[0];
    const float* w   = (const float*)d_in[1];

    float* out_q   = (float*)d_out;                       // 4,194,304
    float* out_idx = (float*)d_out + 4194304;             // 65,536
    float* out_loss= (float*)d_out + 4194304 + 65536;     // 64

    float* partials = (float*)d_ws;                       // NBLOCKS floats

    vq_main_kernel<<<NBLOCKS, BLOCK, 0, stream>>>(inp, w, out_q, out_idx, partials);
    vq_loss_kernel<<<1, 64, 0, stream>>>(partials, out_loss);
}

// Round 2
// 126.527 us; speedup vs baseline: 2.5404x; 2.5404x over previous
//
#include <hip/hip_runtime.h>
#include <hip/hip_bf16.h>

// VectorQuantizer: B=64, C=64, H=32, W=32, K=1024
// d_in[0]: inputs  [B,C,H,W] fp32  (4,194,304)
// d_in[1]: weight  [K,C]     fp32  (65,536)
// d_out (float32, concat):
//   [0,          4194304)  quantized_st [B,C,H,W]
//   [4194304,    4259840)  indices      [B,H,W]  (written as float)
//   [4259840,    4259904)  loss         [B]

#define VQ_C    64
#define VQ_K    1024
#define VQ_HW   1024            // H*W
#define VQ_B    64
#define VQ_ROWS (VQ_B * VQ_HW)  // 65536
#define BLOCK   256
#define NBLOCKS (VQ_ROWS / BLOCK)  // 256
#define NSEG    4
#define SK      (VQ_K / NSEG)   // 256 codes per segment

// ---------------- split path: partial argmin per K-segment ----------------
__global__ __launch_bounds__(BLOCK, 4) void vq_partial_kernel(
    const float* __restrict__ inp,   // [B,C,H,W]
    const float* __restrict__ w,     // [K,C]
    float* __restrict__ dist_ws,     // [NSEG][VQ_ROWS]
    int*   __restrict__ idx_ws)      // [NSEG][VQ_ROWS]
{
    __shared__ float se2[SK];

    const int tid = threadIdx.x;
    const int seg = blockIdx.y;
    const int k0  = seg * SK;

    // ---- ||e_k||^2 for this segment's 256 codes (identical expr to ref path) ----
    {
        const float* wr = w + (size_t)(k0 + tid) * VQ_C;
        float s0 = 0.f, s1 = 0.f, s2 = 0.f, s3 = 0.f;
        #pragma unroll
        for (int c = 0; c < VQ_C; c += 4) {
            s0 = fmaf(wr[c + 0], wr[c + 0], s0);
            s1 = fmaf(wr[c + 1], wr[c + 1], s1);
            s2 = fmaf(wr[c + 2], wr[c + 2], s2);
            s3 = fmaf(wr[c + 3], wr[c + 3], s3);
        }
        se2[tid] = (s0 + s1) + (s2 + s3);
    }
    __syncthreads();

    // ---- load this thread's row x; coalesced across the wave per channel ----
    const int r  = blockIdx.x * BLOCK + tid;
    const int b  = r >> 10;
    const int hw = r & (VQ_HW - 1);

    const float* xin = inp + (size_t)b * (VQ_C * VQ_HW) + hw;
    float x[VQ_C];
    #pragma unroll
    for (int c = 0; c < VQ_C; ++c) x[c] = xin[(size_t)c * VQ_HW];

    // Pin x in VGPRs: forbid rematerialization / AGPR round-trips in the hot loop.
    #pragma unroll
    for (int c = 0; c < VQ_C; ++c) asm volatile("" : "+v"(x[c]));

    float sx0 = 0.f, sx1 = 0.f, sx2 = 0.f, sx3 = 0.f;
    #pragma unroll
    for (int c = 0; c < VQ_C; c += 4) {
        sx0 = fmaf(x[c + 0], x[c + 0], sx0);
        sx1 = fmaf(x[c + 1], x[c + 1], sx1);
        sx2 = fmaf(x[c + 2], x[c + 2], sx2);
        sx3 = fmaf(x[c + 3], x[c + 3], sx3);
    }
    const float sx = (sx0 + sx1) + (sx2 + sx3);

    // ---- argmin over this segment's codes; weight address is wave-uniform ----
    float best  = 3.402823466e38f;
    int   bestk = k0;
    const float* wseg = w + (size_t)k0 * VQ_C;
    #pragma unroll 2
    for (int k = 0; k < SK; ++k) {
        const float* wr = wseg + (size_t)k * VQ_C;
        float d0 = 0.f, d1 = 0.f, d2 = 0.f, d3 = 0.f;
        #pragma unroll
        for (int c = 0; c < VQ_C; c += 4) {
            d0 = fmaf(wr[c + 0], x[c + 0], d0);
            d1 = fmaf(wr[c + 1], x[c + 1], d1);
            d2 = fmaf(wr[c + 2], x[c + 2], d2);
            d3 = fmaf(wr[c + 3], x[c + 3], d3);
        }
        const float dot = (d0 + d1) + (d2 + d3);
        const float d = (sx + se2[k]) - 2.f * dot;   // identical expr/order to ref path
        if (d < best) { best = d; bestk = k0 + k; }
    }

    dist_ws[(size_t)seg * VQ_ROWS + r] = best;
    idx_ws [(size_t)seg * VQ_ROWS + r] = bestk;
}

// ---------------- merge partials + epilogue ----------------
__global__ __launch_bounds__(BLOCK) void vq_finalize_kernel(
    const float* __restrict__ inp,
    const float* __restrict__ w,
    const float* __restrict__ dist_ws,
    const int*   __restrict__ idx_ws,
    float* __restrict__ out_q,
    float* __restrict__ out_idx,
    float* __restrict__ partials)    // [NBLOCKS]
{
    __shared__ float red[BLOCK];
    const int tid = threadIdx.x;
    const int r   = blockIdx.x * BLOCK + tid;
    const int b   = r >> 10;
    const int hw  = r & (VQ_HW - 1);

    // strict < over ascending segments == global lowest-index-wins argmin
    float best  = dist_ws[r];
    int   bestk = idx_ws[r];
    #pragma unroll
    for (int s = 1; s < NSEG; ++s) {
        const float d  = dist_ws[(size_t)s * VQ_ROWS + r];
        const int   kk = idx_ws [(size_t)s * VQ_ROWS + r];
        if (d < best) { best = d; bestk = kk; }
    }

    const float* xin  = inp + (size_t)b * (VQ_C * VQ_HW) + hw;
    const float* q    = w + (size_t)bestk * VQ_C;      // per-lane gather, L2-hot
    float*       outr = out_q + (size_t)b * (VQ_C * VQ_HW) + hw;

    float sd0 = 0.f, sd1 = 0.f, sd2 = 0.f, sd3 = 0.f;
    #pragma unroll
    for (int c = 0; c < VQ_C; c += 4) {
        float x0 = xin[(size_t)(c + 0) * VQ_HW];
        float x1 = xin[(size_t)(c + 1) * VQ_HW];
        float x2 = xin[(size_t)(c + 2) * VQ_HW];
        float x3 = xin[(size_t)(c + 3) * VQ_HW];
        float q0 = q[c + 0], q1 = q[c + 1], q2 = q[c + 2], q3 = q[c + 3];
        outr[(size_t)(c + 0) * VQ_HW] = x0 + (q0 - x0);
        outr[(size_t)(c + 1) * VQ_HW] = x1 + (q1 - x1);
        outr[(size_t)(c + 2) * VQ_HW] = x2 + (q2 - x2);
        outr[(size_t)(c + 3) * VQ_HW] = x3 + (q3 - x3);
        float e0 = q0 - x0, e1 = q1 - x1, e2 = q2 - x2, e3 = q3 - x3;
        sd0 = fmaf(e0, e0, sd0);
        sd1 = fmaf(e1, e1, sd1);
        sd2 = fmaf(e2, e2, sd2);
        sd3 = fmaf(e3, e3, sd3);
    }
    out_idx[r] = (float)bestk;

    red[tid] = (sd0 + sd1) + (sd2 + sd3);
    __syncthreads();
    #pragma unroll
    for (int s = BLOCK / 2; s > 0; s >>= 1) {
        if (tid < s) red[tid] += red[tid + s];
        __syncthreads();
    }
    if (tid == 0) partials[blockIdx.x] = red[0];
}

__global__ __launch_bounds__(64) void vq_loss_kernel(
    const float* __restrict__ partials,  // [NBLOCKS], 4 blocks per b
    float* __restrict__ loss)            // [B]
{
    const int b = threadIdx.x;
    const float s = (partials[4 * b + 0] + partials[4 * b + 1])
                  + (partials[4 * b + 2] + partials[4 * b + 3]);
    const float L = s * (1.0f / 65536.0f);
    loss[b] = L + 0.25f * L;
}

// ---------------- fallback monolithic path (small ws) ----------------
__global__ __launch_bounds__(BLOCK) void vq_main_kernel(
    const float* __restrict__ inp,
    const float* __restrict__ w,
    float* __restrict__ out_q,
    float* __restrict__ out_idx,
    float* __restrict__ partials)
{
    __shared__ float se2[VQ_K];
    __shared__ float red[BLOCK];
    const int tid = threadIdx.x;

    for (int k = tid; k < VQ_K; k += BLOCK) {
        const float* wr = w + k * VQ_C;
        float s0 = 0.f, s1 = 0.f, s2 = 0.f, s3 = 0.f;
        #pragma unroll
        for (int c = 0; c < VQ_C; c += 4) {
            s0 = fmaf(wr[c + 0], wr[c + 0], s0);
            s1 = fmaf(wr[c + 1], wr[c + 1], s1);
            s2 = fmaf(wr[c + 2], wr[c + 2], s2);
            s3 = fmaf(wr[c + 3], wr[c + 3], s3);
        }
        se2[k] = (s0 + s1) + (s2 + s3);
    }
    __syncthreads();

    const int r  = blockIdx.x * BLOCK + tid;
    const int b  = r >> 10;
    const int hw = r & (VQ_HW - 1);

    const float* xin = inp + (size_t)b * (VQ_C * VQ_HW) + hw;
    float x[VQ_C];
    #pragma unroll
    for (int c = 0; c < VQ_C; ++c) x[c] = xin[(size_t)c * VQ_HW];
    #pragma unroll
    for (int c = 0; c < VQ_C; ++c) asm volatile("" : "+v"(x[c]));

    float sx0 = 0.f, sx1 = 0.f, sx2 = 0.f, sx3 = 0.f;
    #pragma unroll
    for (int c = 0; c < VQ_C; c += 4) {
        sx0 = fmaf(x[c + 0], x[c + 0], sx0);
        sx1 = fmaf(x[c + 1], x[c + 1], sx1);
        sx2 = fmaf(x[c + 2], x[c + 2], sx2);
        sx3 = fmaf(x[c + 3], x[c + 3], sx3);
    }
    const float sx = (sx0 + sx1) + (sx2 + sx3);

    float best = 3.402823466e38f;
    int bestk = 0;
    for (int k = 0; k < VQ_K; ++k) {
        const float* wr = w + (size_t)k * VQ_C;
        float d0 = 0.f, d1 = 0.f, d2 = 0.f, d3 = 0.f;
        #pragma unroll
        for (int c = 0; c < VQ_C; c += 4) {
            d0 = fmaf(wr[c + 0], x[c + 0], d0);
            d1 = fmaf(wr[c + 1], x[c + 1], d1);
            d2 = fmaf(wr[c + 2], x[c + 2], d2);
            d3 = fmaf(wr[c + 3], x[c + 3], d3);
        }
        const float dot = (d0 + d1) + (d2 + d3);
        const float d = (sx + se2[k]) - 2.f * dot;
        if (d < best) { best = d; bestk = k; }
    }

    const float* q = w + (size_t)bestk * VQ_C;
    float* outr = out_q + (size_t)b * (VQ_C * VQ_HW) + hw;
    float sd0 = 0.f, sd1 = 0.f, sd2 = 0.f, sd3 = 0.f;
    #pragma unroll
    for (int c = 0; c < VQ_C; c += 4) {
        float q0 = q[c + 0], q1 = q[c + 1], q2 = q[c + 2], q3 = q[c + 3];
        float x0 = x[c + 0], x1 = x[c + 1], x2 = x[c + 2], x3 = x[c + 3];
        outr[(size_t)(c + 0) * VQ_HW] = x0 + (q0 - x0);
        outr[(size_t)(c + 1) * VQ_HW] = x1 + (q1 - x1);
        outr[(size_t)(c + 2) * VQ_HW] = x2 + (q2 - x2);
        outr[(size_t)(c + 3) * VQ_HW] = x3 + (q3 - x3);
        float e0 = q0 - x0, e1 = q1 - x1, e2 = q2 - x2, e3 = q3 - x3;
        sd0 = fmaf(e0, e0, sd0);
        sd1 = fmaf(e1, e1, sd1);
        sd2 = fmaf(e2, e2, sd2);
        sd3 = fmaf(e3, e3, sd3);
    }
    out_idx[r] = (float)bestk;

    red[tid] = (sd0 + sd1) + (sd2 + sd3);
    __syncthreads();
    #pragma unroll
    for (int s = BLOCK / 2; s > 0; s >>= 1) {
        if (tid < s) red[tid] += red[tid + s];
        __syncthreads();
    }
    if (tid == 0) partials[blockIdx.x] = red[0];
}

extern "C" void kernel_launch(void* const* d_in, const int* in_sizes, int n_in,
                              void* d_out, int out_size, void* d_ws, size_t ws_size,
                              hipStream_t stream) {
    const float* inp = (const float*)d_in[0];
    const float* w   = (const float*)d_in[1];

    float* out_q    = (float*)d_out;
    float* out_idx  = (float*)d_out + 4194304;
    float* out_loss = (float*)d_out + 4194304 + 65536;

    // ws layout (split path): dist[4][65536] f32 | idx[4][65536] i32 | partials[256] f32
    const size_t dist_bytes = (size_t)NSEG * VQ_ROWS * sizeof(float);   // 1 MB
    const size_t idx_bytes  = (size_t)NSEG * VQ_ROWS * sizeof(int);     // 1 MB
    const size_t part_bytes = (size_t)NBLOCKS * sizeof(float);          // 1 KB
    const size_t need = dist_bytes + idx_bytes + part_bytes;

    if (ws_size >= need) {
        float* dist_ws  = (float*)d_ws;
        int*   idx_ws   = (int*)((char*)d_ws + dist_bytes);
        float* partials = (float*)((char*)d_ws + dist_bytes + idx_bytes);

        vq_partial_kernel<<<dim3(NBLOCKS, NSEG), BLOCK, 0, stream>>>(inp, w, dist_ws, idx_ws);
        vq_finalize_kernel<<<NBLOCKS, BLOCK, 0, stream>>>(inp, w, dist_ws, idx_ws,
                                                          out_q, out_idx, partials);
        vq_loss_kernel<<<1, 64, 0, stream>>>(partials, out_loss);
    } else {
        float* partials = (float*)d_ws;  // 256 floats
        vq_main_kernel<<<NBLOCKS, BLOCK, 0, stream>>>(inp, w, out_q, out_idx, partials);
        vq_loss_kernel<<<1, 64, 0, stream>>>(partials, out_loss);
    }
}

// Round 3
// 120.240 us; speedup vs baseline: 2.6732x; 1.0523x over previous
//
#include <hip/hip_runtime.h>
#include <hip/hip_bf16.h>

// VectorQuantizer: B=64, C=64, H=32, W=32, K=1024
// d_in[0]: inputs  [B,C,H,W] fp32  (4,194,304)
// d_in[1]: weight  [K,C]     fp32  (65,536)
// d_out (float32, concat):
//   [0,          4194304)  quantized_st [B,C,H,W]
//   [4194304,    4259840)  indices      [B,H,W]  (written as float)
//   [4259840,    4259904)  loss         [B]

#define VQ_C    64
#define VQ_K    1024
#define VQ_HW   1024            // H*W
#define VQ_B    64
#define VQ_ROWS (VQ_B * VQ_HW)  // 65536
#define BLOCK   256
#define NBLOCKS (VQ_ROWS / BLOCK)  // 256

typedef float f32x16 __attribute__((ext_vector_type(16)));

// x element c (0..63) from four 16-wide vectors; c is a literal after unroll.
#define XC(c) ((c) < 16 ? x0[(c) & 15] : (c) < 32 ? x1[(c) & 15] \
               : (c) < 48 ? x2[(c) & 15] : x3[(c) & 15])

// ---------------- split path: partial argmin per K-segment ----------------
template <int SK>
__global__ __launch_bounds__(BLOCK, 4) void vq_partial(
    const float* __restrict__ inp,   // [B,C,H,W]
    const float* __restrict__ w,     // [K,C]
    float* __restrict__ dist_ws,     // [NSEG][VQ_ROWS]
    int*   __restrict__ idx_ws)      // [NSEG][VQ_ROWS]
{
    __shared__ float se2[SK];

    const int tid = threadIdx.x;
    const int seg = blockIdx.y;
    const int k0  = seg * SK;

    // ---- ||e_k||^2 for this segment's codes (identical expr to round-2) ----
    if (tid < SK) {
        const float* wr = w + (size_t)(k0 + tid) * VQ_C;
        float s0 = 0.f, s1 = 0.f, s2 = 0.f, s3 = 0.f;
        #pragma unroll
        for (int c = 0; c < VQ_C; c += 4) {
            s0 = fmaf(wr[c + 0], wr[c + 0], s0);
            s1 = fmaf(wr[c + 1], wr[c + 1], s1);
            s2 = fmaf(wr[c + 2], wr[c + 2], s2);
            s3 = fmaf(wr[c + 3], wr[c + 3], s3);
        }
        se2[tid] = (s0 + s1) + (s2 + s3);
    }
    __syncthreads();

    // ---- load this thread's row x; coalesced across the wave per channel ----
    const int r  = blockIdx.x * BLOCK + tid;
    const int b  = r >> 10;
    const int hw = r & (VQ_HW - 1);

    const float* xin = inp + (size_t)b * (VQ_C * VQ_HW) + hw;
    f32x16 x0, x1, x2, x3;
    #pragma unroll
    for (int c = 0; c < 16; ++c) {
        x0[c] = xin[(size_t)(c +  0) * VQ_HW];
        x1[c] = xin[(size_t)(c + 16) * VQ_HW];
        x2[c] = xin[(size_t)(c + 32) * VQ_HW];
        x3[c] = xin[(size_t)(c + 48) * VQ_HW];
    }
    // Single opaque def over all 64 VGPRs: not rematerializable, keeps x resident.
    asm volatile("" : "+v"(x0), "+v"(x1), "+v"(x2), "+v"(x3));

    float sx0 = 0.f, sx1 = 0.f, sx2 = 0.f, sx3 = 0.f;
    #pragma unroll
    for (int c = 0; c < VQ_C; c += 4) {
        sx0 = fmaf(XC(c + 0), XC(c + 0), sx0);
        sx1 = fmaf(XC(c + 1), XC(c + 1), sx1);
        sx2 = fmaf(XC(c + 2), XC(c + 2), sx2);
        sx3 = fmaf(XC(c + 3), XC(c + 3), sx3);
    }
    const float sx = (sx0 + sx1) + (sx2 + sx3);

    // ---- argmin over this segment's codes; weight address is wave-uniform ----
    float best  = 3.402823466e38f;
    int   bestk = k0;
    const float* wseg = w + (size_t)k0 * VQ_C;
    #pragma unroll 2
    for (int k = 0; k < SK; ++k) {
        const float* wr = wseg + (size_t)k * VQ_C;
        float d0 = 0.f, d1 = 0.f, d2 = 0.f, d3 = 0.f;
        #pragma unroll
        for (int c = 0; c < VQ_C; c += 4) {
            d0 = fmaf(wr[c + 0], XC(c + 0), d0);
            d1 = fmaf(wr[c + 1], XC(c + 1), d1);
            d2 = fmaf(wr[c + 2], XC(c + 2), d2);
            d3 = fmaf(wr[c + 3], XC(c + 3), d3);
        }
        const float dot = (d0 + d1) + (d2 + d3);
        const float d = (sx + se2[k]) - 2.f * dot;   // identical expr/order to round-2
        if (d < best) { best = d; bestk = k0 + k; }
    }

    dist_ws[(size_t)seg * VQ_ROWS + r] = best;
    idx_ws [(size_t)seg * VQ_ROWS + r] = bestk;
}

// ---------------- merge partials + epilogue ----------------
__global__ __launch_bounds__(BLOCK) void vq_finalize_kernel(
    const float* __restrict__ inp,
    const float* __restrict__ w,
    const float* __restrict__ dist_ws,
    const int*   __restrict__ idx_ws,
    float* __restrict__ out_q,
    float* __restrict__ out_idx,
    float* __restrict__ partials,    // [NBLOCKS]
    int nseg)
{
    __shared__ float red[BLOCK];
    const int tid = threadIdx.x;
    const int r   = blockIdx.x * BLOCK + tid;
    const int b   = r >> 10;
    const int hw  = r & (VQ_HW - 1);

    // strict < over ascending segments == global lowest-index-wins argmin
    float best  = dist_ws[r];
    int   bestk = idx_ws[r];
    for (int s = 1; s < nseg; ++s) {
        const float d  = dist_ws[(size_t)s * VQ_ROWS + r];
        const int   kk = idx_ws [(size_t)s * VQ_ROWS + r];
        if (d < best) { best = d; bestk = kk; }
    }

    const float* xin  = inp + (size_t)b * (VQ_C * VQ_HW) + hw;
    const float* q    = w + (size_t)bestk * VQ_C;      // per-lane gather, L2-hot
    float*       outr = out_q + (size_t)b * (VQ_C * VQ_HW) + hw;

    float sd0 = 0.f, sd1 = 0.f, sd2 = 0.f, sd3 = 0.f;
    #pragma unroll
    for (int c = 0; c < VQ_C; c += 4) {
        float x0 = xin[(size_t)(c + 0) * VQ_HW];
        float x1 = xin[(size_t)(c + 1) * VQ_HW];
        float x2 = xin[(size_t)(c + 2) * VQ_HW];
        float x3 = xin[(size_t)(c + 3) * VQ_HW];
        float q0 = q[c + 0], q1 = q[c + 1], q2 = q[c + 2], q3 = q[c + 3];
        outr[(size_t)(c + 0) * VQ_HW] = x0 + (q0 - x0);
        outr[(size_t)(c + 1) * VQ_HW] = x1 + (q1 - x1);
        outr[(size_t)(c + 2) * VQ_HW] = x2 + (q2 - x2);
        outr[(size_t)(c + 3) * VQ_HW] = x3 + (q3 - x3);
        float e0 = q0 - x0, e1 = q1 - x1, e2 = q2 - x2, e3 = q3 - x3;
        sd0 = fmaf(e0, e0, sd0);
        sd1 = fmaf(e1, e1, sd1);
        sd2 = fmaf(e2, e2, sd2);
        sd3 = fmaf(e3, e3, sd3);
    }
    out_idx[r] = (float)bestk;

    red[tid] = (sd0 + sd1) + (sd2 + sd3);
    __syncthreads();
    #pragma unroll
    for (int s = BLOCK / 2; s > 0; s >>= 1) {
        if (tid < s) red[tid] += red[tid + s];
        __syncthreads();
    }
    if (tid == 0) partials[blockIdx.x] = red[0];
}

__global__ __launch_bounds__(64) void vq_loss_kernel(
    const float* __restrict__ partials,  // [NBLOCKS], 4 blocks per b
    float* __restrict__ loss)            // [B]
{
    const int b = threadIdx.x;
    const float s = (partials[4 * b + 0] + partials[4 * b + 1])
                  + (partials[4 * b + 2] + partials[4 * b + 3]);
    const float L = s * (1.0f / 65536.0f);
    loss[b] = L + 0.25f * L;
}

// ---------------- fallback monolithic path (tiny ws) ----------------
__global__ __launch_bounds__(BLOCK) void vq_main_kernel(
    const float* __restrict__ inp,
    const float* __restrict__ w,
    float* __restrict__ out_q,
    float* __restrict__ out_idx,
    float* __restrict__ partials)
{
    __shared__ float se2[VQ_K];
    __shared__ float red[BLOCK];
    const int tid = threadIdx.x;

    for (int k = tid; k < VQ_K; k += BLOCK) {
        const float* wr = w + k * VQ_C;
        float s0 = 0.f, s1 = 0.f, s2 = 0.f, s3 = 0.f;
        #pragma unroll
        for (int c = 0; c < VQ_C; c += 4) {
            s0 = fmaf(wr[c + 0], wr[c + 0], s0);
            s1 = fmaf(wr[c + 1], wr[c + 1], s1);
            s2 = fmaf(wr[c + 2], wr[c + 2], s2);
            s3 = fmaf(wr[c + 3], wr[c + 3], s3);
        }
        se2[k] = (s0 + s1) + (s2 + s3);
    }
    __syncthreads();

    const int r  = blockIdx.x * BLOCK + tid;
    const int b  = r >> 10;
    const int hw = r & (VQ_HW - 1);

    const float* xin = inp + (size_t)b * (VQ_C * VQ_HW) + hw;
    f32x16 x0, x1, x2, x3;
    #pragma unroll
    for (int c = 0; c < 16; ++c) {
        x0[c] = xin[(size_t)(c +  0) * VQ_HW];
        x1[c] = xin[(size_t)(c + 16) * VQ_HW];
        x2[c] = xin[(size_t)(c + 32) * VQ_HW];
        x3[c] = xin[(size_t)(c + 48) * VQ_HW];
    }
    asm volatile("" : "+v"(x0), "+v"(x1), "+v"(x2), "+v"(x3));

    float sx0 = 0.f, sx1 = 0.f, sx2 = 0.f, sx3 = 0.f;
    #pragma unroll
    for (int c = 0; c < VQ_C; c += 4) {
        sx0 = fmaf(XC(c + 0), XC(c + 0), sx0);
        sx1 = fmaf(XC(c + 1), XC(c + 1), sx1);
        sx2 = fmaf(XC(c + 2), XC(c + 2), sx2);
        sx3 = fmaf(XC(c + 3), XC(c + 3), sx3);
    }
    const float sx = (sx0 + sx1) + (sx2 + sx3);

    float best = 3.402823466e38f;
    int bestk = 0;
    for (int k = 0; k < VQ_K; ++k) {
        const float* wr = w + (size_t)k * VQ_C;
        float d0 = 0.f, d1 = 0.f, d2 = 0.f, d3 = 0.f;
        #pragma unroll
        for (int c = 0; c < VQ_C; c += 4) {
            d0 = fmaf(wr[c + 0], XC(c + 0), d0);
            d1 = fmaf(wr[c + 1], XC(c + 1), d1);
            d2 = fmaf(wr[c + 2], XC(c + 2), d2);
            d3 = fmaf(wr[c + 3], XC(c + 3), d3);
        }
        const float dot = (d0 + d1) + (d2 + d3);
        const float d = (sx + se2[k]) - 2.f * dot;
        if (d < best) { best = d; bestk = k; }
    }

    const float* q = w + (size_t)bestk * VQ_C;
    float* outr = out_q + (size_t)b * (VQ_C * VQ_HW) + hw;
    float sd0 = 0.f, sd1 = 0.f, sd2 = 0.f, sd3 = 0.f;
    #pragma unroll
    for (int c = 0; c < VQ_C; c += 4) {
        float q0 = q[c + 0], q1 = q[c + 1], q2 = q[c + 2], q3 = q[c + 3];
        float xv0 = XC(c + 0), xv1 = XC(c + 1), xv2 = XC(c + 2), xv3 = XC(c + 3);
        outr[(size_t)(c + 0) * VQ_HW] = xv0 + (q0 - xv0);
        outr[(size_t)(c + 1) * VQ_HW] = xv1 + (q1 - xv1);
        outr[(size_t)(c + 2) * VQ_HW] = xv2 + (q2 - xv2);
        outr[(size_t)(c + 3) * VQ_HW] = xv3 + (q3 - xv3);
        float e0 = q0 - xv0, e1 = q1 - xv1, e2 = q2 - xv2, e3 = q3 - xv3;
        sd0 = fmaf(e0, e0, sd0);
        sd1 = fmaf(e1, e1, sd1);
        sd2 = fmaf(e2, e2, sd2);
        sd3 = fmaf(e3, e3, sd3);
    }
    out_idx[r] = (float)bestk;

    red[tid] = (sd0 + sd1) + (sd2 + sd3);
    __syncthreads();
    #pragma unroll
    for (int s = BLOCK / 2; s > 0; s >>= 1) {
        if (tid < s) red[tid] += red[tid + s];
        __syncthreads();
    }
    if (tid == 0) partials[blockIdx.x] = red[0];
}

extern "C" void kernel_launch(void* const* d_in, const int* in_sizes, int n_in,
                              void* d_out, int out_size, void* d_ws, size_t ws_size,
                              hipStream_t stream) {
    const float* inp = (const float*)d_in[0];
    const float* w   = (const float*)d_in[1];

    float* out_q    = (float*)d_out;
    float* out_idx  = (float*)d_out + 4194304;
    float* out_loss = (float*)d_out + 4194304 + 65536;

    const size_t part_bytes = (size_t)NBLOCKS * sizeof(float);  // 1 KB

    // pick largest nseg whose scratch fits: dist[ns][ROWS] f32 | idx[ns][ROWS] i32 | partials
    int nseg = 0;
    if (ws_size >= (size_t)8 * VQ_ROWS * 8 + part_bytes)      nseg = 8;
    else if (ws_size >= (size_t)4 * VQ_ROWS * 8 + part_bytes) nseg = 4;

    if (nseg > 0) {
        const size_t dist_bytes = (size_t)nseg * VQ_ROWS * sizeof(float);
        const size_t idx_bytes  = (size_t)nseg * VQ_ROWS * sizeof(int);
        float* dist_ws  = (float*)d_ws;
        int*   idx_ws   = (int*)((char*)d_ws + dist_bytes);
        float* partials = (float*)((char*)d_ws + dist_bytes + idx_bytes);

        if (nseg == 8) {
            vq_partial<VQ_K / 8><<<dim3(NBLOCKS, 8), BLOCK, 0, stream>>>(inp, w, dist_ws, idx_ws);
        } else {
            vq_partial<VQ_K / 4><<<dim3(NBLOCKS, 4), BLOCK, 0, stream>>>(inp, w, dist_ws, idx_ws);
        }
        vq_finalize_kernel<<<NBLOCKS, BLOCK, 0, stream>>>(inp, w, dist_ws, idx_ws,
                                                          out_q, out_idx, partials, nseg);
        vq_loss_kernel<<<1, 64, 0, stream>>>(partials, out_loss);
    } else {
        float* partials = (float*)d_ws;  // 256 floats
        vq_main_kernel<<<NBLOCKS, BLOCK, 0, stream>>>(inp, w, out_q, out_idx, partials);
        vq_loss_kernel<<<1, 64, 0, stream>>>(partials, out_loss);
    }
}